// Round 5
// baseline (1239.105 us; speedup 1.0000x reference)
//
#include <hip/hip_runtime.h>
#include <hip/hip_bf16.h>

// B=4, N=4096, C=128, K=16. float32 in/out (reference file is all jnp.float32;
// R2/R3's bit-identical absmax proved the I/O-dtype misread). Single fused
// kernel, one wave per point, zero d_ws usage. Discrete decisions (KNN set,
// eig branches/signs) replicate numpy-f32: sgemm FMA-chain dot, numpy op
// order for pairwise, and a BLAS-call-faithful f32 ssyevd port
// (ssytd2 + ssteqr QL/QR + sormtr, LAPACK>=3.10 slartg, copysignf SIGN).
// R4 fix: mid-function '#pragma clang fp contract(off)' is illegal -> Phase 3
// now uses explicit __fmul_rn/__fadd_rn (also FMA-contraction-proof).
#define N_ 4096
#define C_ 128
#define K_ 16
#define NPT 16384

__device__ __forceinline__ float wave_sum64(float v) {
#pragma unroll
  for (int off = 32; off >= 1; off >>= 1) v += __shfl_xor(v, off, 64);
  return v;
}

// ---------------- LAPACK f32 helpers (gfortran SIGN == copysignf) ----------------

__device__ __forceinline__ float sign_f(float a, float b) {
  return copysignf(fabsf(a), b);
}

__device__ float lapy2_f(float x, float y) {
#pragma clang fp contract(off)
  float xa = fabsf(x), ya = fabsf(y);
  float w = fmaxf(xa, ya), z = fminf(xa, ya);
  if (z == 0.0f) return w;
  float t = z / w;
  return w * sqrtf(1.0f + t * t);
}

// LAPACK >= 3.10 slartg (numpy wheels bundle OpenBLAS w/ LAPACK >= 3.10)
__device__ void lartg_f(float f, float g, float& c, float& s, float& r) {
#pragma clang fp contract(off)
  if (g == 0.0f) {
    c = 1.0f; s = 0.0f; r = f;
  } else if (f == 0.0f) {
    c = 0.0f; s = copysignf(1.0f, g); r = fabsf(g);
  } else {
    float d = sqrtf(f * f + g * g);
    c = fabsf(f) / d;
    r = sign_f(d, f);
    s = g / r;
  }
}

__device__ void laev2_f(float a, float b, float cc, float& rt1, float& rt2,
                        float& cs1, float& sn1) {
#pragma clang fp contract(off)
  float sm = a + cc;
  float df = a - cc;
  float adf = fabsf(df);
  float tb = b + b;
  float ab = fabsf(tb);
  float acmx, acmn;
  if (fabsf(a) > fabsf(cc)) { acmx = a; acmn = cc; } else { acmx = cc; acmn = a; }
  float rt;
  if (adf > ab) {
    float t = ab / adf; rt = adf * sqrtf(1.0f + t * t);
  } else if (adf < ab) {
    float t = adf / ab; rt = ab * sqrtf(1.0f + t * t);
  } else {
    rt = ab * sqrtf(2.0f);
  }
  int sgn1;
  if (sm < 0.0f) {
    rt1 = 0.5f * (sm - rt); sgn1 = -1;
    rt2 = (acmx / rt1) * acmn - (b / rt1) * b;
  } else if (sm > 0.0f) {
    rt1 = 0.5f * (sm + rt); sgn1 = 1;
    rt2 = (acmx / rt1) * acmn - (b / rt1) * b;
  } else {
    rt1 = 0.5f * rt; rt2 = -0.5f * rt; sgn1 = 1;
  }
  float cs; int sgn2;
  if (df >= 0.0f) { cs = df + rt; sgn2 = 1; } else { cs = df - rt; sgn2 = -1; }
  float acs = fabsf(cs);
  if (acs > ab) {
    float ct = -tb / cs;
    sn1 = 1.0f / sqrtf(1.0f + ct * ct);
    cs1 = ct * sn1;
  } else {
    if (ab == 0.0f) { cs1 = 1.0f; sn1 = 0.0f; }
    else {
      float tn = -cs / tb;
      cs1 = 1.0f / sqrtf(1.0f + tn * tn);
      sn1 = tn * cs1;
    }
  }
  if (sgn1 == sgn2) { float tn = cs1; cs1 = -sn1; sn1 = tn; }
}

// ssteqr('I') specialized to n=3, f32 constants (segment anorm for these
// covariances sits inside [ssfmin, ssfmax] -> no LASCL scaling path).
__device__ void steqr3_f(float d[3], float e[2], float Z[3][3]) {
#pragma clang fp contract(off)
  const int n = 3;
  const float eps = 5.9604644775390625e-08f;   // 2^-24 = SLAMCH('E')
  const float eps2 = eps * eps;
  const float safmin = 1.17549435e-38f;
  const int nmaxit = n * 30;
  int jtot = 0;
  int l1 = 1;

  for (int og = 0; og < 16; ++og) {
    if (l1 > n) break;
    if (l1 > 1) e[l1 - 2] = 0.0f;
    int m, l, lend;
    if (l1 <= n - 1) {
      bool found = false;
      for (m = l1; m <= n - 1; ++m) {
        float tst = fabsf(e[m - 1]);
        if (tst == 0.0f) { found = true; break; }
        if (tst <= (sqrtf(fabsf(d[m - 1])) * sqrtf(fabsf(d[m]))) * eps) {
          e[m - 1] = 0.0f; found = true; break;
        }
      }
      if (!found) m = n;
    } else {
      m = n;
    }
    l = l1; lend = m; l1 = m + 1;
    if (lend == l) continue;
    if (fabsf(d[lend - 1]) < fabsf(d[l - 1])) { int t = l; l = lend; lend = t; }

    if (lend > l) {
      // ---- QL iteration ----
      for (int it = 0; it < 128; ++it) {
        int mm;
        if (l != lend) {
          bool f2 = false;
          for (mm = l; mm <= lend - 1; ++mm) {
            float tst = e[mm - 1] * e[mm - 1];
            if (tst <= (eps2 * fabsf(d[mm - 1])) * fabsf(d[mm]) + safmin) { f2 = true; break; }
          }
          if (!f2) mm = lend;
        } else mm = lend;
        if (mm < lend) e[mm - 1] = 0.0f;
        float p = d[l - 1];
        if (mm == l) {
          d[l - 1] = p; ++l;
          if (l <= lend) continue;
          break;
        }
        if (mm == l + 1) {
          float rt1, rt2, cc, ss;
          laev2_f(d[l - 1], e[l - 1], d[l], rt1, rt2, cc, ss);
          for (int r = 0; r < n; ++r) {
            float temp = Z[r][l];
            Z[r][l] = cc * temp - ss * Z[r][l - 1];
            Z[r][l - 1] = ss * temp + cc * Z[r][l - 1];
          }
          d[l - 1] = rt1; d[l] = rt2; e[l - 1] = 0.0f;
          l += 2;
          if (l <= lend) continue;
          break;
        }
        if (jtot == nmaxit) break;
        ++jtot;
        float g = (d[l] - p) / (2.0f * e[l - 1]);
        float r = lapy2_f(g, 1.0f);
        g = d[mm - 1] - p + e[l - 1] / (g + sign_f(r, g));
        float s = 1.0f, c = 1.0f;
        p = 0.0f;
        float csv[2], snv[2];
        for (int i = mm - 1; i >= l; --i) {
          float f = s * e[i - 1];
          float bb = c * e[i - 1];
          lartg_f(g, f, c, s, r);
          if (i != mm - 1) e[i] = r;
          g = d[i] - p;
          r = (d[i - 1] - g) * s + 2.0f * c * bb;
          p = s * r;
          d[i] = g + p;
          g = c * r - bb;
          csv[i - l] = c;
          snv[i - l] = -s;
        }
        int mml = mm - l;
        for (int j = mml; j >= 1; --j) {
          float cc = csv[j - 1], ss = snv[j - 1];
          for (int r2 = 0; r2 < n; ++r2) {
            float temp = Z[r2][l + j - 1];
            Z[r2][l + j - 1] = cc * temp - ss * Z[r2][l + j - 2];
            Z[r2][l + j - 2] = ss * temp + cc * Z[r2][l + j - 2];
          }
        }
        d[l - 1] -= p;
        e[l - 1] = g;
      }
    } else {
      // ---- QR iteration ----
      for (int it = 0; it < 128; ++it) {
        int mm;
        if (l != lend) {
          bool f2 = false;
          for (mm = l; mm >= lend + 1; --mm) {
            float tst = e[mm - 2] * e[mm - 2];
            if (tst <= (eps2 * fabsf(d[mm - 1])) * fabsf(d[mm - 2]) + safmin) { f2 = true; break; }
          }
          if (!f2) mm = lend;
        } else mm = lend;
        if (mm > lend) e[mm - 2] = 0.0f;
        float p = d[l - 1];
        if (mm == l) {
          d[l - 1] = p; --l;
          if (l >= lend) continue;
          break;
        }
        if (mm == l - 1) {
          float rt1, rt2, cc, ss;
          laev2_f(d[l - 2], e[l - 2], d[l - 1], rt1, rt2, cc, ss);
          for (int r = 0; r < n; ++r) {
            float temp = Z[r][l - 1];
            Z[r][l - 1] = cc * temp - ss * Z[r][l - 2];
            Z[r][l - 2] = ss * temp + cc * Z[r][l - 2];
          }
          d[l - 2] = rt1; d[l - 1] = rt2; e[l - 2] = 0.0f;
          l -= 2;
          if (l >= lend) continue;
          break;
        }
        if (jtot == nmaxit) break;
        ++jtot;
        float g = (d[l - 2] - p) / (2.0f * e[l - 2]);
        float r = lapy2_f(g, 1.0f);
        g = d[mm - 1] - p + e[l - 2] / (g + sign_f(r, g));
        float s = 1.0f, c = 1.0f;
        p = 0.0f;
        float csv[2], snv[2];
        for (int i = mm; i <= l - 1; ++i) {
          float f = s * e[i - 1];
          float bb = c * e[i - 1];
          lartg_f(g, f, c, s, r);
          if (i != mm) e[i - 2] = r;
          g = d[i - 1] - p;
          r = (d[i] - g) * s + 2.0f * c * bb;
          p = s * r;
          d[i - 1] = g + p;
          g = c * r - bb;
          csv[i - mm] = c;
          snv[i - mm] = s;
        }
        int lm = l - mm;
        for (int j = 1; j <= lm; ++j) {
          float cc = csv[j - 1], ss = snv[j - 1];
          for (int r2 = 0; r2 < n; ++r2) {
            float temp = Z[r2][mm + j - 1];
            Z[r2][mm + j - 1] = cc * temp - ss * Z[r2][mm + j - 2];
            Z[r2][mm + j - 2] = ss * temp + cc * Z[r2][mm + j - 2];
          }
        }
        d[l - 1] -= p;
        e[l - 2] = g;
      }
    }
  }
  // ascending selection sort with column swaps (ssteqr tail)
  for (int ii = 2; ii <= n; ++ii) {
    int i = ii - 1, k = i;
    float p = d[i - 1];
    for (int j = ii; j <= n; ++j) {
      if (d[j - 1] < p) { k = j; p = d[j - 1]; }
    }
    if (k != i) {
      d[k - 1] = d[i - 1]; d[i - 1] = p;
      for (int r = 0; r < n; ++r) {
        float t = Z[r][i - 1]; Z[r][i - 1] = Z[r][k - 1]; Z[r][k - 1] = t;
      }
    }
  }
}

// ssyevd(jobz='V', uplo='L') for 3x3: ssytd2 (BLAS-order-faithful) + ssteqr
// + sormtr. A lower triangle: A00, A10, A20, A11, A21, A22.
__device__ void eig3_f(float A00, float A10, float A20,
                       float A11, float A21, float A22, float Z[3][3]) {
#pragma clang fp contract(off)
  float d[3], e[2];
  float tau = 0.0f, v2 = 0.0f;
  d[0] = A00;
  float xnorm = fabsf(A20);
  if (xnorm == 0.0f) {
    tau = 0.0f; v2 = 0.0f;
    e[0] = A10; d[1] = A11; e[1] = A21; d[2] = A22;
  } else {
    // slarfg
    float beta = -sign_f(lapy2_f(A10, xnorm), A10);
    tau = (beta - A10) / beta;
    float inv = 1.0f / (A10 - beta);   // SSCAL: reciprocal then multiply
    v2 = A20 * inv;
    e[0] = beta;
    // SSYMV lower (n=2, alpha=tau, x=(1,v2), beta=0) exact accumulation order
    float x0 = tau * A11;
    float x1 = tau * A21;
    float tmp2 = A21 * v2;
    x0 = x0 + tau * tmp2;
    x1 = x1 + (tau * v2) * A22;
    // SDOT serial, then ALPHA = -HALF*TAUI*DOT (left-assoc)
    float dotv = x0 + x1 * v2;
    float aw = (-0.5f * tau) * dotv;
    // SAXPY
    float w0 = x0 + aw;
    float w1 = x1 + aw * v2;
    // SSYR2 lower, alpha=-1: A(i,j) = (A(i,j) + x(i)*temp1) + y(i)*temp2
    d[1] = (A11 - w0) - w0;
    float pq = v2 * w0;
    e[1] = (A21 - pq) - w1;
    float pr = v2 * w1;
    d[2] = (A22 - pr) - pr;
  }
  Z[0][0] = 1.0f; Z[0][1] = 0.0f; Z[0][2] = 0.0f;
  Z[1][0] = 0.0f; Z[1][1] = 1.0f; Z[1][2] = 0.0f;
  Z[2][0] = 0.0f; Z[2][1] = 0.0f; Z[2][2] = 1.0f;
  steqr3_f(d, e, Z);
  // sormtr('L','L','N'): Z := H1*Z, v=[0;1;v2]
  if (tau != 0.0f) {
    for (int j = 0; j < 3; ++j) {
      float sum = Z[1][j] + v2 * Z[2][j];
      float tw = tau * sum;
      Z[1][j] = Z[1][j] - tw;
      Z[2][j] = Z[2][j] - v2 * tw;
    }
  }
}

// ---------------- Fused kernel: one wave per point, zero workspace ----------------
__global__ __launch_bounds__(256) void fused_kernel(
    const float* __restrict__ xyz, const float* __restrict__ feats,
    const float* __restrict__ geo_w1, const float* __restrict__ geo_b1,
    const float* __restrict__ geo_g1, const float* __restrict__ geo_be1,
    const float* __restrict__ geo_w2, const float* __restrict__ geo_b2,
    const float* __restrict__ diff_w1, const float* __restrict__ diff_b1,
    const float* __restrict__ diff_g1, const float* __restrict__ diff_be1,
    const float* __restrict__ diff_w2, const float* __restrict__ diff_b2,
    const float* __restrict__ ep_w1, const float* __restrict__ ep_b1,
    const float* __restrict__ ep_w2, const float* __restrict__ ep_b2,
    const float* __restrict__ ref_w1, const float* __restrict__ ref_b1,
    const float* __restrict__ ref_g1, const float* __restrict__ ref_be1,
    float* __restrict__ out, float* __restrict__ out_prob) {

  // 32 KB union: KNN merge lists overlaid (barrier-separated) with MLP buffers.
  __shared__ union SMem {
    struct { float v[4][64][K_]; int id[4][64][K_]; } knn;   // 16 KB + 16 KB
    struct { float y[4][64]; float buf[4][256]; } mlp;       // 5 KB
  } sm;

  const int wave = threadIdx.x >> 6;
  const int lane = threadIdx.x & 63;
  const int p = blockIdx.x * 4 + wave;
  const int b = p >> 12;
  const int i = p & 4095;
  const float* xb = xyz + (size_t)b * (N_ * 3);
  const float qx = xb[3 * i];
  const float qy = xb[3 * i + 1];
  const float qz = xb[3 * i + 2];
  // numpy: xx = sum(x*x, axis=2) -> sequential mul/add
  const float qxx =
      __fadd_rn(__fadd_rn(__fmul_rn(qx, qx), __fmul_rn(qy, qy)), __fmul_rn(qz, qz));

  // ---- Phase 1: per-lane top-16 over this lane's 64 strided candidates ----
  float pv[K_];
  int pi[K_];
#pragma unroll
  for (int k = 0; k < K_; ++k) { pv[k] = -INFINITY; pi[k] = 0x7fffffff; }

#pragma unroll 2
  for (int t = 0; t < N_ / 64; ++t) {
    const int j = t * 64 + lane;
    const float x = xb[3 * j];
    const float y = xb[3 * j + 1];
    const float z = xb[3 * j + 2];
    // sgemm micro-kernel: acc=0; k-ascending fma chain (fma(x0,y0,0)==mul)
    const float dot = __fmaf_rn(qz, z, __fmaf_rn(qy, y, __fmul_rn(qx, x)));
    const float xxj =
        __fadd_rn(__fadd_rn(__fmul_rn(x, x), __fmul_rn(y, y)), __fmul_rn(z, z));
    // numpy elementwise: pairwise = ((-xx_i) - inner) - xx_j
    const float inner = __fmul_rn(-2.0f, dot);
    const float pval = __fsub_rn(__fsub_rn(-qxx, inner), xxj);
    if ((pval > pv[K_ - 1]) || (pval == pv[K_ - 1] && j < pi[K_ - 1])) {
#pragma unroll
      for (int q = K_ - 1; q >= 1; --q) {
        bool cq = (pval > pv[q]) || (pval == pv[q] && j < pi[q]);
        bool cp = (pval > pv[q - 1]) || (pval == pv[q - 1] && j < pi[q - 1]);
        float nv = cq ? (cp ? pv[q - 1] : pval) : pv[q];
        int ni = cq ? (cp ? pi[q - 1] : j) : pi[q];
        pv[q] = nv; pi[q] = ni;
      }
      if ((pval > pv[0]) || (pval == pv[0] && j < pi[0])) { pv[0] = pval; pi[0] = j; }
    }
  }

#pragma unroll
  for (int k = 0; k < K_; ++k) {
    sm.knn.v[wave][lane][k] = pv[k];
    sm.knn.id[wave][lane][k] = pi[k];
  }
  __syncthreads();

  // ---- Phase 2: 64-way tournament merge; winners broadcast to ALL lanes ----
  int nidx[K_];
  int h = 0;
#pragma unroll
  for (int k = 0; k < K_; ++k) {
    float v = (h < K_) ? sm.knn.v[wave][lane][h] : -INFINITY;
    int ji = (h < K_) ? sm.knn.id[wave][lane][h] : 0x7fffffff;
    int ln = lane;
#pragma unroll
    for (int off = 32; off >= 1; off >>= 1) {
      float ov = __shfl_xor(v, off, 64);
      int oj = __shfl_xor(ji, off, 64);
      int ol = __shfl_xor(ln, off, 64);
      bool take = (ov > v) || (ov == v && oj < ji);
      if (take) { v = ov; ji = oj; ln = ol; }
    }
    nidx[k] = ji & (N_ - 1);   // defensive: bug => wrong answer, not a fault
    if (lane == ln) ++h;
  }
  __syncthreads();   // union reuse boundary (knn lists -> mlp buffers)

  // ---- Phase 3: rel_pos/cov/eig/gfeat (f32, numpy op order, all lanes) ----
  // Explicit _rn intrinsics: exact numpy sequential order, no FMA contraction.
  float c00 = 0, c01 = 0, c02 = 0, c11 = 0, c12 = 0, c22 = 0;
  float mrx = 0, mry = 0, mrz = 0, md = 0;
#pragma unroll
  for (int k = 0; k < K_; ++k) {
    const int j = nidx[k];
    const float rx = __fsub_rn(xb[3 * j], qx);
    const float ry = __fsub_rn(xb[3 * j + 1], qy);
    const float rz = __fsub_rn(xb[3 * j + 2], qz);
    c00 = __fadd_rn(c00, __fmul_rn(rx, rx));
    c01 = __fadd_rn(c01, __fmul_rn(rx, ry));
    c02 = __fadd_rn(c02, __fmul_rn(rx, rz));
    c11 = __fadd_rn(c11, __fmul_rn(ry, ry));
    c12 = __fadd_rn(c12, __fmul_rn(ry, rz));
    c22 = __fadd_rn(c22, __fmul_rn(rz, rz));
    mrx = __fadd_rn(mrx, rx);
    mry = __fadd_rn(mry, ry);
    mrz = __fadd_rn(mrz, rz);
    const float nn = __fadd_rn(__fadd_rn(__fmul_rn(rx, rx), __fmul_rn(ry, ry)),
                               __fmul_rn(rz, rz));
    md = __fadd_rn(md, sqrtf(nn));
  }
  const float s16 = 0.0625f;  // /16 exact
  float Z[3][3];
  eig3_f(__fmul_rn(c00, s16), __fmul_rn(c01, s16), __fmul_rn(c02, s16),
         __fmul_rn(c11, s16), __fmul_rn(c12, s16), __fmul_rn(c22, s16), Z);
  float gf[10];
  gf[0] = Z[0][0]; gf[1] = Z[1][0]; gf[2] = Z[2][0];   // normal    (col 0)
  gf[3] = Z[0][2]; gf[4] = Z[1][2]; gf[5] = Z[2][2];   // curvature (col 2)
  gf[6] = __fmul_rn(mrx, s16); gf[7] = __fmul_rn(mry, s16);
  gf[8] = __fmul_rn(mrz, s16);
  gf[9] = __fmul_rn(md, s16);

  // ---- Phase 4: geo MLP (lane = hidden unit) ----
  float acc = 0.0f;
#pragma unroll
  for (int ii = 0; ii < 10; ++ii) acc += gf[ii] * geo_w1[ii * 64 + lane];
  acc += geo_b1[lane];
  {
    float m = wave_sum64(acc) * (1.0f / 64.0f);
    float xm = acc - m;
    float var = wave_sum64(xm * xm) * (1.0f / 64.0f);
    float yv = xm * (1.0f / sqrtf(var + 1e-5f)) * geo_g1[lane] + geo_be1[lane];
    sm.mlp.y[wave][lane] = fmaxf(yv, 0.0f);
  }
  __syncthreads();
  float ge = 0.0f;
#pragma unroll 8
  for (int jj = 0; jj < 64; ++jj) ge += sm.mlp.y[wave][jj] * geo_w2[jj * 64 + lane];
  ge += geo_b2[lane];

  // ---- Phase 5: feat_diff + diff MLP ----
  const float* fb = feats + (size_t)b * N_ * C_;
  const float* fi = fb + (size_t)i * C_;
  const float f0 = fi[lane];
  const float f1 = fi[64 + lane];
  float s0 = 0.0f, s1 = 0.0f;
#pragma unroll
  for (int k = 0; k < K_; ++k) {
    const float* fj = fb + (size_t)nidx[k] * C_;
    s0 += fabsf(f0 - fj[lane]);
    s1 += fabsf(f1 - fj[64 + lane]);
  }
  s0 *= (1.0f / 16.0f);
  s1 *= (1.0f / 16.0f);
  sm.mlp.buf[wave][lane] = s0;
  sm.mlp.buf[wave][64 + lane] = s1;
  __syncthreads();
  float acc2 = 0.0f;
#pragma unroll 8
  for (int c = 0; c < 128; ++c) acc2 += sm.mlp.buf[wave][c] * diff_w1[c * 64 + lane];
  acc2 += diff_b1[lane];
  {
    float m = wave_sum64(acc2) * (1.0f / 64.0f);
    float xm = acc2 - m;
    float var = wave_sum64(xm * xm) * (1.0f / 64.0f);
    float yv = xm * (1.0f / sqrtf(var + 1e-5f)) * diff_g1[lane] + diff_be1[lane];
    sm.mlp.y[wave][lane] = fmaxf(yv, 0.0f);
  }
  __syncthreads();
  float de = 0.0f;
#pragma unroll 8
  for (int jj = 0; jj < 64; ++jj) de += sm.mlp.y[wave][jj] * diff_w2[jj * 64 + lane];
  de += diff_b2[lane];

  // ---- Phase 6: edge prob + enhanced + refine ----
  __syncthreads();
  sm.mlp.buf[wave][lane] = ge;
  sm.mlp.buf[wave][64 + lane] = de;
  __syncthreads();
  float hh = 0.0f;
  if (lane < 32) {
    float a = 0.0f;
#pragma unroll 8
    for (int c = 0; c < 128; ++c) a += sm.mlp.buf[wave][c] * ep_w1[c * 32 + lane];
    a += ep_b1[lane];
    hh = fmaxf(a, 0.0f) * ep_w2[lane];
  }
  float tsum = wave_sum64(hh) + ep_b2[0];
  float prob = 1.0f / (1.0f + expf(-tsum));
  __syncthreads();
  sm.mlp.buf[wave][lane] = f0;
  sm.mlp.buf[wave][64 + lane] = f1;
  sm.mlp.buf[wave][128 + lane] = ge * prob;
  sm.mlp.buf[wave][192 + lane] = de * prob;
  __syncthreads();
  float a0 = 0.0f, a1 = 0.0f;
#pragma unroll 4
  for (int c = 0; c < 256; ++c) {
    float ec = sm.mlp.buf[wave][c];
    a0 += ec * ref_w1[c * 128 + lane];
    a1 += ec * ref_w1[c * 128 + 64 + lane];
  }
  a0 += ref_b1[lane];
  a1 += ref_b1[64 + lane];
  float mm2 = wave_sum64(a0 + a1) * (1.0f / 128.0f);
  float d0 = a0 - mm2, d1 = a1 - mm2;
  float var2 = wave_sum64(d0 * d0 + d1 * d1) * (1.0f / 128.0f);
  float rs = 1.0f / sqrtf(var2 + 1e-5f);
  float y0 = d0 * rs * ref_g1[lane] + ref_be1[lane];
  float y1 = d1 * rs * ref_g1[64 + lane] + ref_be1[64 + lane];
  y0 = fmaxf(y0, 0.0f) + f0;
  y1 = fmaxf(y1, 0.0f) + f1;
  out[(size_t)p * 128 + lane] = y0;
  out[(size_t)p * 128 + 64 + lane] = y1;
  if (lane == 0) out_prob[p] = prob;
}

extern "C" void kernel_launch(void* const* d_in, const int* in_sizes, int n_in,
                              void* d_out, int out_size, void* d_ws, size_t ws_size,
                              hipStream_t stream) {
  const float* xyz = (const float*)d_in[0];
  const float* features = (const float*)d_in[1];
  const float* geo_w1 = (const float*)d_in[2];
  const float* geo_b1 = (const float*)d_in[3];
  const float* geo_g1 = (const float*)d_in[4];
  const float* geo_be1 = (const float*)d_in[5];
  const float* geo_w2 = (const float*)d_in[6];
  const float* geo_b2 = (const float*)d_in[7];
  const float* diff_w1 = (const float*)d_in[8];
  const float* diff_b1 = (const float*)d_in[9];
  const float* diff_g1 = (const float*)d_in[10];
  const float* diff_be1 = (const float*)d_in[11];
  const float* diff_w2 = (const float*)d_in[12];
  const float* diff_b2 = (const float*)d_in[13];
  const float* ep_w1 = (const float*)d_in[14];
  const float* ep_b1 = (const float*)d_in[15];
  const float* ep_w2 = (const float*)d_in[16];
  const float* ep_b2 = (const float*)d_in[17];
  const float* ref_w1 = (const float*)d_in[18];
  const float* ref_b1 = (const float*)d_in[19];
  const float* ref_g1 = (const float*)d_in[20];
  const float* ref_be1 = (const float*)d_in[21];

  float* out = (float*)d_out;
  float* out_prob = out + (size_t)NPT * C_;   // refined first, then edge_prob

  fused_kernel<<<dim3(NPT / 4), dim3(256), 0, stream>>>(
      xyz, features, geo_w1, geo_b1, geo_g1, geo_be1, geo_w2, geo_b2, diff_w1,
      diff_b1, diff_g1, diff_be1, diff_w2, diff_b2, ep_w1, ep_b1, ep_w2, ep_b2,
      ref_w1, ref_b1, ref_g1, ref_be1, out, out_prob);
}

// Round 6
// 557.097 us; speedup vs baseline: 2.2242x; 2.2242x over previous
//
#include <hip/hip_runtime.h>
#include <hip/hip_bf16.h>

// B=4, N=4096, C=128, K=16. float32 in/out. PASSED at 1200us (R5).
// R6 optimization: (1) packed u64 KNN keys (ordv<<32 | (4095-j)) -- strict
// monotone encoding of numpy's (value desc, index asc) order, so selection is
// bit-identical but insertion stage = 1 u64 cmp + 2 u64 selects;
// (2) unconditional insertion (branch was ~always taken);
// (3) register-resident tournament merge (no LDS -> kills the 3.03e7
//     SQ_LDS_BANK_CONFLICT from the old [64][16] stride);
// (4) xyz staged in a 12KB LDS tile per block (coalesced float4 staging,
//     stride-3 ds_reads = 2-way aliasing = free) instead of per-wave L1
//     thrash of 48KB stride-12 gathers.
// Phases 3-6 (eig, MLPs, output) are byte-identical to the passing R5 code.
#define N_ 4096
#define C_ 128
#define K_ 16
#define NPT 16384

__device__ __forceinline__ float wave_sum64(float v) {
#pragma unroll
  for (int off = 32; off >= 1; off >>= 1) v += __shfl_xor(v, off, 64);
  return v;
}

// ---------------- LAPACK f32 helpers (gfortran SIGN == copysignf) ----------------

__device__ __forceinline__ float sign_f(float a, float b) {
  return copysignf(fabsf(a), b);
}

__device__ float lapy2_f(float x, float y) {
#pragma clang fp contract(off)
  float xa = fabsf(x), ya = fabsf(y);
  float w = fmaxf(xa, ya), z = fminf(xa, ya);
  if (z == 0.0f) return w;
  float t = z / w;
  return w * sqrtf(1.0f + t * t);
}

// LAPACK >= 3.10 slartg
__device__ void lartg_f(float f, float g, float& c, float& s, float& r) {
#pragma clang fp contract(off)
  if (g == 0.0f) {
    c = 1.0f; s = 0.0f; r = f;
  } else if (f == 0.0f) {
    c = 0.0f; s = copysignf(1.0f, g); r = fabsf(g);
  } else {
    float d = sqrtf(f * f + g * g);
    c = fabsf(f) / d;
    r = sign_f(d, f);
    s = g / r;
  }
}

__device__ void laev2_f(float a, float b, float cc, float& rt1, float& rt2,
                        float& cs1, float& sn1) {
#pragma clang fp contract(off)
  float sm = a + cc;
  float df = a - cc;
  float adf = fabsf(df);
  float tb = b + b;
  float ab = fabsf(tb);
  float acmx, acmn;
  if (fabsf(a) > fabsf(cc)) { acmx = a; acmn = cc; } else { acmx = cc; acmn = a; }
  float rt;
  if (adf > ab) {
    float t = ab / adf; rt = adf * sqrtf(1.0f + t * t);
  } else if (adf < ab) {
    float t = adf / ab; rt = ab * sqrtf(1.0f + t * t);
  } else {
    rt = ab * sqrtf(2.0f);
  }
  int sgn1;
  if (sm < 0.0f) {
    rt1 = 0.5f * (sm - rt); sgn1 = -1;
    rt2 = (acmx / rt1) * acmn - (b / rt1) * b;
  } else if (sm > 0.0f) {
    rt1 = 0.5f * (sm + rt); sgn1 = 1;
    rt2 = (acmx / rt1) * acmn - (b / rt1) * b;
  } else {
    rt1 = 0.5f * rt; rt2 = -0.5f * rt; sgn1 = 1;
  }
  float cs; int sgn2;
  if (df >= 0.0f) { cs = df + rt; sgn2 = 1; } else { cs = df - rt; sgn2 = -1; }
  float acs = fabsf(cs);
  if (acs > ab) {
    float ct = -tb / cs;
    sn1 = 1.0f / sqrtf(1.0f + ct * ct);
    cs1 = ct * sn1;
  } else {
    if (ab == 0.0f) { cs1 = 1.0f; sn1 = 0.0f; }
    else {
      float tn = -cs / tb;
      cs1 = 1.0f / sqrtf(1.0f + tn * tn);
      sn1 = tn * cs1;
    }
  }
  if (sgn1 == sgn2) { float tn = cs1; cs1 = -sn1; sn1 = tn; }
}

// ssteqr('I') specialized to n=3, f32 constants.
__device__ void steqr3_f(float d[3], float e[2], float Z[3][3]) {
#pragma clang fp contract(off)
  const int n = 3;
  const float eps = 5.9604644775390625e-08f;   // 2^-24
  const float eps2 = eps * eps;
  const float safmin = 1.17549435e-38f;
  const int nmaxit = n * 30;
  int jtot = 0;
  int l1 = 1;

  for (int og = 0; og < 16; ++og) {
    if (l1 > n) break;
    if (l1 > 1) e[l1 - 2] = 0.0f;
    int m, l, lend;
    if (l1 <= n - 1) {
      bool found = false;
      for (m = l1; m <= n - 1; ++m) {
        float tst = fabsf(e[m - 1]);
        if (tst == 0.0f) { found = true; break; }
        if (tst <= (sqrtf(fabsf(d[m - 1])) * sqrtf(fabsf(d[m]))) * eps) {
          e[m - 1] = 0.0f; found = true; break;
        }
      }
      if (!found) m = n;
    } else {
      m = n;
    }
    l = l1; lend = m; l1 = m + 1;
    if (lend == l) continue;
    if (fabsf(d[lend - 1]) < fabsf(d[l - 1])) { int t = l; l = lend; lend = t; }

    if (lend > l) {
      // ---- QL ----
      for (int it = 0; it < 128; ++it) {
        int mm;
        if (l != lend) {
          bool f2 = false;
          for (mm = l; mm <= lend - 1; ++mm) {
            float tst = e[mm - 1] * e[mm - 1];
            if (tst <= (eps2 * fabsf(d[mm - 1])) * fabsf(d[mm]) + safmin) { f2 = true; break; }
          }
          if (!f2) mm = lend;
        } else mm = lend;
        if (mm < lend) e[mm - 1] = 0.0f;
        float p = d[l - 1];
        if (mm == l) {
          d[l - 1] = p; ++l;
          if (l <= lend) continue;
          break;
        }
        if (mm == l + 1) {
          float rt1, rt2, cc, ss;
          laev2_f(d[l - 1], e[l - 1], d[l], rt1, rt2, cc, ss);
          for (int r = 0; r < n; ++r) {
            float temp = Z[r][l];
            Z[r][l] = cc * temp - ss * Z[r][l - 1];
            Z[r][l - 1] = ss * temp + cc * Z[r][l - 1];
          }
          d[l - 1] = rt1; d[l] = rt2; e[l - 1] = 0.0f;
          l += 2;
          if (l <= lend) continue;
          break;
        }
        if (jtot == nmaxit) break;
        ++jtot;
        float g = (d[l] - p) / (2.0f * e[l - 1]);
        float r = lapy2_f(g, 1.0f);
        g = d[mm - 1] - p + e[l - 1] / (g + sign_f(r, g));
        float s = 1.0f, c = 1.0f;
        p = 0.0f;
        float csv[2], snv[2];
        for (int i = mm - 1; i >= l; --i) {
          float f = s * e[i - 1];
          float bb = c * e[i - 1];
          lartg_f(g, f, c, s, r);
          if (i != mm - 1) e[i] = r;
          g = d[i] - p;
          r = (d[i - 1] - g) * s + 2.0f * c * bb;
          p = s * r;
          d[i] = g + p;
          g = c * r - bb;
          csv[i - l] = c;
          snv[i - l] = -s;
        }
        int mml = mm - l;
        for (int j = mml; j >= 1; --j) {
          float cc = csv[j - 1], ss = snv[j - 1];
          for (int r2 = 0; r2 < n; ++r2) {
            float temp = Z[r2][l + j - 1];
            Z[r2][l + j - 1] = cc * temp - ss * Z[r2][l + j - 2];
            Z[r2][l + j - 2] = ss * temp + cc * Z[r2][l + j - 2];
          }
        }
        d[l - 1] -= p;
        e[l - 1] = g;
      }
    } else {
      // ---- QR ----
      for (int it = 0; it < 128; ++it) {
        int mm;
        if (l != lend) {
          bool f2 = false;
          for (mm = l; mm >= lend + 1; --mm) {
            float tst = e[mm - 2] * e[mm - 2];
            if (tst <= (eps2 * fabsf(d[mm - 1])) * fabsf(d[mm - 2]) + safmin) { f2 = true; break; }
          }
          if (!f2) mm = lend;
        } else mm = lend;
        if (mm > lend) e[mm - 2] = 0.0f;
        float p = d[l - 1];
        if (mm == l) {
          d[l - 1] = p; --l;
          if (l >= lend) continue;
          break;
        }
        if (mm == l - 1) {
          float rt1, rt2, cc, ss;
          laev2_f(d[l - 2], e[l - 2], d[l - 1], rt1, rt2, cc, ss);
          for (int r = 0; r < n; ++r) {
            float temp = Z[r][l - 1];
            Z[r][l - 1] = cc * temp - ss * Z[r][l - 2];
            Z[r][l - 2] = ss * temp + cc * Z[r][l - 2];
          }
          d[l - 2] = rt1; d[l - 1] = rt2; e[l - 2] = 0.0f;
          l -= 2;
          if (l >= lend) continue;
          break;
        }
        if (jtot == nmaxit) break;
        ++jtot;
        float g = (d[l - 2] - p) / (2.0f * e[l - 2]);
        float r = lapy2_f(g, 1.0f);
        g = d[mm - 1] - p + e[l - 2] / (g + sign_f(r, g));
        float s = 1.0f, c = 1.0f;
        p = 0.0f;
        float csv[2], snv[2];
        for (int i = mm; i <= l - 1; ++i) {
          float f = s * e[i - 1];
          float bb = c * e[i - 1];
          lartg_f(g, f, c, s, r);
          if (i != mm) e[i - 2] = r;
          g = d[i - 1] - p;
          r = (d[i] - g) * s + 2.0f * c * bb;
          p = s * r;
          d[i - 1] = g + p;
          g = c * r - bb;
          csv[i - mm] = c;
          snv[i - mm] = s;
        }
        int lm = l - mm;
        for (int j = 1; j <= lm; ++j) {
          float cc = csv[j - 1], ss = snv[j - 1];
          for (int r2 = 0; r2 < n; ++r2) {
            float temp = Z[r2][mm + j - 1];
            Z[r2][mm + j - 1] = cc * temp - ss * Z[r2][mm + j - 2];
            Z[r2][mm + j - 2] = ss * temp + cc * Z[r2][mm + j - 2];
          }
        }
        d[l - 1] -= p;
        e[l - 2] = g;
      }
    }
  }
  // ascending selection sort with column swaps
  for (int ii = 2; ii <= n; ++ii) {
    int i = ii - 1, k = i;
    float p = d[i - 1];
    for (int j = ii; j <= n; ++j) {
      if (d[j - 1] < p) { k = j; p = d[j - 1]; }
    }
    if (k != i) {
      d[k - 1] = d[i - 1]; d[i - 1] = p;
      for (int r = 0; r < n; ++r) {
        float t = Z[r][i - 1]; Z[r][i - 1] = Z[r][k - 1]; Z[r][k - 1] = t;
      }
    }
  }
}

// ssyevd(jobz='V', uplo='L') for 3x3
__device__ void eig3_f(float A00, float A10, float A20,
                       float A11, float A21, float A22, float Z[3][3]) {
#pragma clang fp contract(off)
  float d[3], e[2];
  float tau = 0.0f, v2 = 0.0f;
  d[0] = A00;
  float xnorm = fabsf(A20);
  if (xnorm == 0.0f) {
    tau = 0.0f; v2 = 0.0f;
    e[0] = A10; d[1] = A11; e[1] = A21; d[2] = A22;
  } else {
    float beta = -sign_f(lapy2_f(A10, xnorm), A10);
    tau = (beta - A10) / beta;
    float inv = 1.0f / (A10 - beta);
    v2 = A20 * inv;
    e[0] = beta;
    float x0 = tau * A11;
    float x1 = tau * A21;
    float tmp2 = A21 * v2;
    x0 = x0 + tau * tmp2;
    x1 = x1 + (tau * v2) * A22;
    float dotv = x0 + x1 * v2;
    float aw = (-0.5f * tau) * dotv;
    float w0 = x0 + aw;
    float w1 = x1 + aw * v2;
    d[1] = (A11 - w0) - w0;
    float pq = v2 * w0;
    e[1] = (A21 - pq) - w1;
    float pr = v2 * w1;
    d[2] = (A22 - pr) - pr;
  }
  Z[0][0] = 1.0f; Z[0][1] = 0.0f; Z[0][2] = 0.0f;
  Z[1][0] = 0.0f; Z[1][1] = 1.0f; Z[1][2] = 0.0f;
  Z[2][0] = 0.0f; Z[2][1] = 0.0f; Z[2][2] = 1.0f;
  steqr3_f(d, e, Z);
  if (tau != 0.0f) {
    for (int j = 0; j < 3; ++j) {
      float sum = Z[1][j] + v2 * Z[2][j];
      float tw = tau * sum;
      Z[1][j] = Z[1][j] - tw;
      Z[2][j] = Z[2][j] - v2 * tw;
    }
  }
}

// ---------------- Fused kernel ----------------
__global__ __launch_bounds__(256) void fused_kernel(
    const float* __restrict__ xyz, const float* __restrict__ feats,
    const float* __restrict__ geo_w1, const float* __restrict__ geo_b1,
    const float* __restrict__ geo_g1, const float* __restrict__ geo_be1,
    const float* __restrict__ geo_w2, const float* __restrict__ geo_b2,
    const float* __restrict__ diff_w1, const float* __restrict__ diff_b1,
    const float* __restrict__ diff_g1, const float* __restrict__ diff_be1,
    const float* __restrict__ diff_w2, const float* __restrict__ diff_b2,
    const float* __restrict__ ep_w1, const float* __restrict__ ep_b1,
    const float* __restrict__ ep_w2, const float* __restrict__ ep_b2,
    const float* __restrict__ ref_w1, const float* __restrict__ ref_b1,
    const float* __restrict__ ref_g1, const float* __restrict__ ref_be1,
    float* __restrict__ out, float* __restrict__ out_prob) {

  // 12 KB union: xyz tile (phase 1) overlaid with MLP buffers (phases 4-6).
  __shared__ union SMem {
    float tile[1024 * 3];                               // 12 KB
    struct { float y[4][64]; float buf[4][256]; } mlp;  // 5 KB
  } sm;

  const int wave = threadIdx.x >> 6;
  const int lane = threadIdx.x & 63;
  const int p = blockIdx.x * 4 + wave;   // 4 points/block, same batch b
  const int b = p >> 12;
  const int i = p & 4095;
  const float* xb = xyz + (size_t)b * (N_ * 3);
  const float qx = xb[3 * i];
  const float qy = xb[3 * i + 1];
  const float qz = xb[3 * i + 2];
  const float qxx =
      __fadd_rn(__fadd_rn(__fmul_rn(qx, qx), __fmul_rn(qy, qy)), __fmul_rn(qz, qz));
  const float nqxx = -qxx;

  // ---- Phase 1: per-lane top-16 as packed u64 keys ----
  // key = ordv(pval) << 32 | (4095 - j): u64 '>' == (pval desc, j asc) exactly.
  unsigned long long pk[K_];
#pragma unroll
  for (int k = 0; k < K_; ++k) pk[k] = 0ull;   // sentinel: below every real key

  for (int tile = 0; tile < 4; ++tile) {
    // stage 1024 points (12 KB) cooperatively: 3x float4 per thread
    {
      const float4* gsrc = (const float4*)(xb + tile * 3072);
      float4* ldst = (float4*)sm.tile;
#pragma unroll
      for (int m = 0; m < 3; ++m)
        ldst[threadIdx.x * 3 + m] = gsrc[threadIdx.x * 3 + m];
    }
    __syncthreads();

#pragma unroll 2
    for (int tloc = 0; tloc < 16; ++tloc) {
      const int o3 = (tloc * 64 + lane) * 3;
      const int j = tile * 1024 + tloc * 64 + lane;
      const float x = sm.tile[o3];
      const float y = sm.tile[o3 + 1];
      const float z = sm.tile[o3 + 2];
      // exact numpy-f32 formula (unchanged from passing version)
      const float dot = __fmaf_rn(qz, z, __fmaf_rn(qy, y, __fmul_rn(qx, x)));
      const float xxj =
          __fadd_rn(__fadd_rn(__fmul_rn(x, x), __fmul_rn(y, y)), __fmul_rn(z, z));
      const float inner = __fmul_rn(-2.0f, dot);
      const float pval = __fsub_rn(__fsub_rn(nqxx, inner), xxj);
      // order-preserving f32 -> u32
      const unsigned bits = __float_as_uint(pval);
      const unsigned ordv = bits ^ (unsigned)(((int)bits >> 31) | 0x80000000);
      const unsigned long long key =
          ((unsigned long long)ordv << 32) | (unsigned)(4095 - j);
      // unconditional 16-stage insertion (branch was ~always taken anyway)
      bool c[K_];
#pragma unroll
      for (int q = 0; q < K_; ++q) c[q] = key > pk[q];
#pragma unroll
      for (int q = K_ - 1; q >= 1; --q)
        pk[q] = c[q] ? (c[q - 1] ? pk[q - 1] : key) : pk[q];
      pk[0] = c[0] ? key : pk[0];
    }
    __syncthreads();   // tile reuse boundary
  }

  // ---- Phase 2: register-resident 64-way tournament merge (no LDS) ----
  int nidx[K_];
#pragma unroll
  for (int k = 0; k < K_; ++k) {
    unsigned long long v = pk[0];
    int ln = lane;
#pragma unroll
    for (int off = 32; off >= 1; off >>= 1) {
      unsigned long long ov = __shfl_xor(v, off, 64);
      int ol = __shfl_xor(ln, off, 64);
      if (ov > v) { v = ov; ln = ol; }   // keys distinct (unique idx) => no ties
    }
    nidx[k] = (4095 - (int)(unsigned)(v & 0xFFFFFFFFull)) & (N_ - 1);
    if (lane == ln) {
#pragma unroll
      for (int q = 0; q < K_ - 1; ++q) pk[q] = pk[q + 1];
      pk[K_ - 1] = 0ull;
    }
  }

  // ---- Phase 3: rel_pos/cov/eig/gfeat (byte-identical to passing R5) ----
  float c00 = 0, c01 = 0, c02 = 0, c11 = 0, c12 = 0, c22 = 0;
  float mrx = 0, mry = 0, mrz = 0, md = 0;
#pragma unroll
  for (int k = 0; k < K_; ++k) {
    const int j = nidx[k];
    const float rx = __fsub_rn(xb[3 * j], qx);
    const float ry = __fsub_rn(xb[3 * j + 1], qy);
    const float rz = __fsub_rn(xb[3 * j + 2], qz);
    c00 = __fadd_rn(c00, __fmul_rn(rx, rx));
    c01 = __fadd_rn(c01, __fmul_rn(rx, ry));
    c02 = __fadd_rn(c02, __fmul_rn(rx, rz));
    c11 = __fadd_rn(c11, __fmul_rn(ry, ry));
    c12 = __fadd_rn(c12, __fmul_rn(ry, rz));
    c22 = __fadd_rn(c22, __fmul_rn(rz, rz));
    mrx = __fadd_rn(mrx, rx);
    mry = __fadd_rn(mry, ry);
    mrz = __fadd_rn(mrz, rz);
    const float nn = __fadd_rn(__fadd_rn(__fmul_rn(rx, rx), __fmul_rn(ry, ry)),
                               __fmul_rn(rz, rz));
    md = __fadd_rn(md, sqrtf(nn));
  }
  const float s16 = 0.0625f;
  float Z[3][3];
  eig3_f(__fmul_rn(c00, s16), __fmul_rn(c01, s16), __fmul_rn(c02, s16),
         __fmul_rn(c11, s16), __fmul_rn(c12, s16), __fmul_rn(c22, s16), Z);
  float gf[10];
  gf[0] = Z[0][0]; gf[1] = Z[1][0]; gf[2] = Z[2][0];
  gf[3] = Z[0][2]; gf[4] = Z[1][2]; gf[5] = Z[2][2];
  gf[6] = __fmul_rn(mrx, s16); gf[7] = __fmul_rn(mry, s16);
  gf[8] = __fmul_rn(mrz, s16);
  gf[9] = __fmul_rn(md, s16);

  // ---- Phase 4: geo MLP ----
  float acc = 0.0f;
#pragma unroll
  for (int ii = 0; ii < 10; ++ii) acc += gf[ii] * geo_w1[ii * 64 + lane];
  acc += geo_b1[lane];
  {
    float m = wave_sum64(acc) * (1.0f / 64.0f);
    float xm = acc - m;
    float var = wave_sum64(xm * xm) * (1.0f / 64.0f);
    float yv = xm * (1.0f / sqrtf(var + 1e-5f)) * geo_g1[lane] + geo_be1[lane];
    sm.mlp.y[wave][lane] = fmaxf(yv, 0.0f);
  }
  __syncthreads();
  float ge = 0.0f;
#pragma unroll 8
  for (int jj = 0; jj < 64; ++jj) ge += sm.mlp.y[wave][jj] * geo_w2[jj * 64 + lane];
  ge += geo_b2[lane];

  // ---- Phase 5: feat_diff + diff MLP ----
  const float* fb = feats + (size_t)b * N_ * C_;
  const float* fi = fb + (size_t)i * C_;
  const float f0 = fi[lane];
  const float f1 = fi[64 + lane];
  float s0 = 0.0f, s1 = 0.0f;
#pragma unroll
  for (int k = 0; k < K_; ++k) {
    const float* fj = fb + (size_t)nidx[k] * C_;
    s0 += fabsf(f0 - fj[lane]);
    s1 += fabsf(f1 - fj[64 + lane]);
  }
  s0 *= (1.0f / 16.0f);
  s1 *= (1.0f / 16.0f);
  __syncthreads();   // all lanes done reading mlp.y (geo)
  sm.mlp.buf[wave][lane] = s0;
  sm.mlp.buf[wave][64 + lane] = s1;
  __syncthreads();
  float acc2 = 0.0f;
#pragma unroll 8
  for (int c = 0; c < 128; ++c) acc2 += sm.mlp.buf[wave][c] * diff_w1[c * 64 + lane];
  acc2 += diff_b1[lane];
  __syncthreads();   // all lanes done reading buf before y overwrite barrier below
  {
    float m = wave_sum64(acc2) * (1.0f / 64.0f);
    float xm = acc2 - m;
    float var = wave_sum64(xm * xm) * (1.0f / 64.0f);
    float yv = xm * (1.0f / sqrtf(var + 1e-5f)) * diff_g1[lane] + diff_be1[lane];
    sm.mlp.y[wave][lane] = fmaxf(yv, 0.0f);
  }
  __syncthreads();
  float de = 0.0f;
#pragma unroll 8
  for (int jj = 0; jj < 64; ++jj) de += sm.mlp.y[wave][jj] * diff_w2[jj * 64 + lane];
  de += diff_b2[lane];

  // ---- Phase 6: edge prob + enhanced + refine ----
  __syncthreads();
  sm.mlp.buf[wave][lane] = ge;
  sm.mlp.buf[wave][64 + lane] = de;
  __syncthreads();
  float hh = 0.0f;
  if (lane < 32) {
    float a = 0.0f;
#pragma unroll 8
    for (int c = 0; c < 128; ++c) a += sm.mlp.buf[wave][c] * ep_w1[c * 32 + lane];
    a += ep_b1[lane];
    hh = fmaxf(a, 0.0f) * ep_w2[lane];
  }
  float tsum = wave_sum64(hh) + ep_b2[0];
  float prob = 1.0f / (1.0f + expf(-tsum));
  __syncthreads();
  sm.mlp.buf[wave][lane] = f0;
  sm.mlp.buf[wave][64 + lane] = f1;
  sm.mlp.buf[wave][128 + lane] = ge * prob;
  sm.mlp.buf[wave][192 + lane] = de * prob;
  __syncthreads();
  float a0 = 0.0f, a1 = 0.0f;
#pragma unroll 4
  for (int c = 0; c < 256; ++c) {
    float ec = sm.mlp.buf[wave][c];
    a0 += ec * ref_w1[c * 128 + lane];
    a1 += ec * ref_w1[c * 128 + 64 + lane];
  }
  a0 += ref_b1[lane];
  a1 += ref_b1[64 + lane];
  float mm2 = wave_sum64(a0 + a1) * (1.0f / 128.0f);
  float d0 = a0 - mm2, d1 = a1 - mm2;
  float var2 = wave_sum64(d0 * d0 + d1 * d1) * (1.0f / 128.0f);
  float rs = 1.0f / sqrtf(var2 + 1e-5f);
  float y0 = d0 * rs * ref_g1[lane] + ref_be1[lane];
  float y1 = d1 * rs * ref_g1[64 + lane] + ref_be1[64 + lane];
  y0 = fmaxf(y0, 0.0f) + f0;
  y1 = fmaxf(y1, 0.0f) + f1;
  out[(size_t)p * 128 + lane] = y0;
  out[(size_t)p * 128 + 64 + lane] = y1;
  if (lane == 0) out_prob[p] = prob;
}

extern "C" void kernel_launch(void* const* d_in, const int* in_sizes, int n_in,
                              void* d_out, int out_size, void* d_ws, size_t ws_size,
                              hipStream_t stream) {
  const float* xyz = (const float*)d_in[0];
  const float* features = (const float*)d_in[1];
  const float* geo_w1 = (const float*)d_in[2];
  const float* geo_b1 = (const float*)d_in[3];
  const float* geo_g1 = (const float*)d_in[4];
  const float* geo_be1 = (const float*)d_in[5];
  const float* geo_w2 = (const float*)d_in[6];
  const float* geo_b2 = (const float*)d_in[7];
  const float* diff_w1 = (const float*)d_in[8];
  const float* diff_b1 = (const float*)d_in[9];
  const float* diff_g1 = (const float*)d_in[10];
  const float* diff_be1 = (const float*)d_in[11];
  const float* diff_w2 = (const float*)d_in[12];
  const float* diff_b2 = (const float*)d_in[13];
  const float* ep_w1 = (const float*)d_in[14];
  const float* ep_b1 = (const float*)d_in[15];
  const float* ep_w2 = (const float*)d_in[16];
  const float* ep_b2 = (const float*)d_in[17];
  const float* ref_w1 = (const float*)d_in[18];
  const float* ref_b1 = (const float*)d_in[19];
  const float* ref_g1 = (const float*)d_in[20];
  const float* ref_be1 = (const float*)d_in[21];

  float* out = (float*)d_out;
  float* out_prob = out + (size_t)NPT * C_;

  fused_kernel<<<dim3(NPT / 4), dim3(256), 0, stream>>>(
      xyz, features, geo_w1, geo_b1, geo_g1, geo_be1, geo_w2, geo_b2, diff_w1,
      diff_b1, diff_g1, diff_be1, diff_w2, diff_b2, ep_w1, ep_b1, ep_w2, ep_b2,
      ref_w1, ref_b1, ref_g1, ref_be1, out, out_prob);
}

// Round 7
// 480.456 us; speedup vs baseline: 2.5790x; 1.1595x over previous
//
#include <hip/hip_runtime.h>
#include <hip/hip_bf16.h>

// B=4, N=4096, C=128, K=16. float32 in/out. R6 passed at 507us.
// R7: (1) per-lane top-4 u64 keys + provably-exact rare fallback (16-deep,
// re-scan from LDS tile) -- insertion 80->20 instr/candidate;
// (2) whole-batch 48KB xyz LDS stage, ONE barrier total;
// (3) MLP matvecs via __shfl dynamic-index broadcast (bitwise-identical
// accumulation order), zero LDS / zero barriers in phases 4-6.
// Distance formula, eig, and all sum orders byte-identical to passing R6.
#define N_ 4096
#define C_ 128
#define K_ 16
#define NPT 16384

__device__ __forceinline__ float wave_sum64(float v) {
#pragma unroll
  for (int off = 32; off >= 1; off >>= 1) v += __shfl_xor(v, off, 64);
  return v;
}

// ---------------- LAPACK f32 helpers (gfortran SIGN == copysignf) ----------------

__device__ __forceinline__ float sign_f(float a, float b) {
  return copysignf(fabsf(a), b);
}

__device__ float lapy2_f(float x, float y) {
#pragma clang fp contract(off)
  float xa = fabsf(x), ya = fabsf(y);
  float w = fmaxf(xa, ya), z = fminf(xa, ya);
  if (z == 0.0f) return w;
  float t = z / w;
  return w * sqrtf(1.0f + t * t);
}

// LAPACK >= 3.10 slartg
__device__ void lartg_f(float f, float g, float& c, float& s, float& r) {
#pragma clang fp contract(off)
  if (g == 0.0f) {
    c = 1.0f; s = 0.0f; r = f;
  } else if (f == 0.0f) {
    c = 0.0f; s = copysignf(1.0f, g); r = fabsf(g);
  } else {
    float d = sqrtf(f * f + g * g);
    c = fabsf(f) / d;
    r = sign_f(d, f);
    s = g / r;
  }
}

__device__ void laev2_f(float a, float b, float cc, float& rt1, float& rt2,
                        float& cs1, float& sn1) {
#pragma clang fp contract(off)
  float sm = a + cc;
  float df = a - cc;
  float adf = fabsf(df);
  float tb = b + b;
  float ab = fabsf(tb);
  float acmx, acmn;
  if (fabsf(a) > fabsf(cc)) { acmx = a; acmn = cc; } else { acmx = cc; acmn = a; }
  float rt;
  if (adf > ab) {
    float t = ab / adf; rt = adf * sqrtf(1.0f + t * t);
  } else if (adf < ab) {
    float t = adf / ab; rt = ab * sqrtf(1.0f + t * t);
  } else {
    rt = ab * sqrtf(2.0f);
  }
  int sgn1;
  if (sm < 0.0f) {
    rt1 = 0.5f * (sm - rt); sgn1 = -1;
    rt2 = (acmx / rt1) * acmn - (b / rt1) * b;
  } else if (sm > 0.0f) {
    rt1 = 0.5f * (sm + rt); sgn1 = 1;
    rt2 = (acmx / rt1) * acmn - (b / rt1) * b;
  } else {
    rt1 = 0.5f * rt; rt2 = -0.5f * rt; sgn1 = 1;
  }
  float cs; int sgn2;
  if (df >= 0.0f) { cs = df + rt; sgn2 = 1; } else { cs = df - rt; sgn2 = -1; }
  float acs = fabsf(cs);
  if (acs > ab) {
    float ct = -tb / cs;
    sn1 = 1.0f / sqrtf(1.0f + ct * ct);
    cs1 = ct * sn1;
  } else {
    if (ab == 0.0f) { cs1 = 1.0f; sn1 = 0.0f; }
    else {
      float tn = -cs / tb;
      cs1 = 1.0f / sqrtf(1.0f + tn * tn);
      sn1 = tn * cs1;
    }
  }
  if (sgn1 == sgn2) { float tn = cs1; cs1 = -sn1; sn1 = tn; }
}

// ssteqr('I') specialized to n=3, f32 constants.
__device__ void steqr3_f(float d[3], float e[2], float Z[3][3]) {
#pragma clang fp contract(off)
  const int n = 3;
  const float eps = 5.9604644775390625e-08f;   // 2^-24
  const float eps2 = eps * eps;
  const float safmin = 1.17549435e-38f;
  const int nmaxit = n * 30;
  int jtot = 0;
  int l1 = 1;

  for (int og = 0; og < 16; ++og) {
    if (l1 > n) break;
    if (l1 > 1) e[l1 - 2] = 0.0f;
    int m, l, lend;
    if (l1 <= n - 1) {
      bool found = false;
      for (m = l1; m <= n - 1; ++m) {
        float tst = fabsf(e[m - 1]);
        if (tst == 0.0f) { found = true; break; }
        if (tst <= (sqrtf(fabsf(d[m - 1])) * sqrtf(fabsf(d[m]))) * eps) {
          e[m - 1] = 0.0f; found = true; break;
        }
      }
      if (!found) m = n;
    } else {
      m = n;
    }
    l = l1; lend = m; l1 = m + 1;
    if (lend == l) continue;
    if (fabsf(d[lend - 1]) < fabsf(d[l - 1])) { int t = l; l = lend; lend = t; }

    if (lend > l) {
      // ---- QL ----
      for (int it = 0; it < 128; ++it) {
        int mm;
        if (l != lend) {
          bool f2 = false;
          for (mm = l; mm <= lend - 1; ++mm) {
            float tst = e[mm - 1] * e[mm - 1];
            if (tst <= (eps2 * fabsf(d[mm - 1])) * fabsf(d[mm]) + safmin) { f2 = true; break; }
          }
          if (!f2) mm = lend;
        } else mm = lend;
        if (mm < lend) e[mm - 1] = 0.0f;
        float p = d[l - 1];
        if (mm == l) {
          d[l - 1] = p; ++l;
          if (l <= lend) continue;
          break;
        }
        if (mm == l + 1) {
          float rt1, rt2, cc, ss;
          laev2_f(d[l - 1], e[l - 1], d[l], rt1, rt2, cc, ss);
          for (int r = 0; r < n; ++r) {
            float temp = Z[r][l];
            Z[r][l] = cc * temp - ss * Z[r][l - 1];
            Z[r][l - 1] = ss * temp + cc * Z[r][l - 1];
          }
          d[l - 1] = rt1; d[l] = rt2; e[l - 1] = 0.0f;
          l += 2;
          if (l <= lend) continue;
          break;
        }
        if (jtot == nmaxit) break;
        ++jtot;
        float g = (d[l] - p) / (2.0f * e[l - 1]);
        float r = lapy2_f(g, 1.0f);
        g = d[mm - 1] - p + e[l - 1] / (g + sign_f(r, g));
        float s = 1.0f, c = 1.0f;
        p = 0.0f;
        float csv[2], snv[2];
        for (int i = mm - 1; i >= l; --i) {
          float f = s * e[i - 1];
          float bb = c * e[i - 1];
          lartg_f(g, f, c, s, r);
          if (i != mm - 1) e[i] = r;
          g = d[i] - p;
          r = (d[i - 1] - g) * s + 2.0f * c * bb;
          p = s * r;
          d[i] = g + p;
          g = c * r - bb;
          csv[i - l] = c;
          snv[i - l] = -s;
        }
        int mml = mm - l;
        for (int j = mml; j >= 1; --j) {
          float cc = csv[j - 1], ss = snv[j - 1];
          for (int r2 = 0; r2 < n; ++r2) {
            float temp = Z[r2][l + j - 1];
            Z[r2][l + j - 1] = cc * temp - ss * Z[r2][l + j - 2];
            Z[r2][l + j - 2] = ss * temp + cc * Z[r2][l + j - 2];
          }
        }
        d[l - 1] -= p;
        e[l - 1] = g;
      }
    } else {
      // ---- QR ----
      for (int it = 0; it < 128; ++it) {
        int mm;
        if (l != lend) {
          bool f2 = false;
          for (mm = l; mm >= lend + 1; --mm) {
            float tst = e[mm - 2] * e[mm - 2];
            if (tst <= (eps2 * fabsf(d[mm - 1])) * fabsf(d[mm - 2]) + safmin) { f2 = true; break; }
          }
          if (!f2) mm = lend;
        } else mm = lend;
        if (mm > lend) e[mm - 2] = 0.0f;
        float p = d[l - 1];
        if (mm == l) {
          d[l - 1] = p; --l;
          if (l >= lend) continue;
          break;
        }
        if (mm == l - 1) {
          float rt1, rt2, cc, ss;
          laev2_f(d[l - 2], e[l - 2], d[l - 1], rt1, rt2, cc, ss);
          for (int r = 0; r < n; ++r) {
            float temp = Z[r][l - 1];
            Z[r][l - 1] = cc * temp - ss * Z[r][l - 2];
            Z[r][l - 2] = ss * temp + cc * Z[r][l - 2];
          }
          d[l - 2] = rt1; d[l - 1] = rt2; e[l - 2] = 0.0f;
          l -= 2;
          if (l >= lend) continue;
          break;
        }
        if (jtot == nmaxit) break;
        ++jtot;
        float g = (d[l - 2] - p) / (2.0f * e[l - 2]);
        float r = lapy2_f(g, 1.0f);
        g = d[mm - 1] - p + e[l - 2] / (g + sign_f(r, g));
        float s = 1.0f, c = 1.0f;
        p = 0.0f;
        float csv[2], snv[2];
        for (int i = mm; i <= l - 1; ++i) {
          float f = s * e[i - 1];
          float bb = c * e[i - 1];
          lartg_f(g, f, c, s, r);
          if (i != mm) e[i - 2] = r;
          g = d[i - 1] - p;
          r = (d[i] - g) * s + 2.0f * c * bb;
          p = s * r;
          d[i - 1] = g + p;
          g = c * r - bb;
          csv[i - mm] = c;
          snv[i - mm] = s;
        }
        int lm = l - mm;
        for (int j = 1; j <= lm; ++j) {
          float cc = csv[j - 1], ss = snv[j - 1];
          for (int r2 = 0; r2 < n; ++r2) {
            float temp = Z[r2][mm + j - 1];
            Z[r2][mm + j - 1] = cc * temp - ss * Z[r2][mm + j - 2];
            Z[r2][mm + j - 2] = ss * temp + cc * Z[r2][mm + j - 2];
          }
        }
        d[l - 1] -= p;
        e[l - 2] = g;
      }
    }
  }
  // ascending selection sort with column swaps
  for (int ii = 2; ii <= n; ++ii) {
    int i = ii - 1, k = i;
    float p = d[i - 1];
    for (int j = ii; j <= n; ++j) {
      if (d[j - 1] < p) { k = j; p = d[j - 1]; }
    }
    if (k != i) {
      d[k - 1] = d[i - 1]; d[i - 1] = p;
      for (int r = 0; r < n; ++r) {
        float t = Z[r][i - 1]; Z[r][i - 1] = Z[r][k - 1]; Z[r][k - 1] = t;
      }
    }
  }
}

// ssyevd(jobz='V', uplo='L') for 3x3
__device__ void eig3_f(float A00, float A10, float A20,
                       float A11, float A21, float A22, float Z[3][3]) {
#pragma clang fp contract(off)
  float d[3], e[2];
  float tau = 0.0f, v2 = 0.0f;
  d[0] = A00;
  float xnorm = fabsf(A20);
  if (xnorm == 0.0f) {
    tau = 0.0f; v2 = 0.0f;
    e[0] = A10; d[1] = A11; e[1] = A21; d[2] = A22;
  } else {
    float beta = -sign_f(lapy2_f(A10, xnorm), A10);
    tau = (beta - A10) / beta;
    float inv = 1.0f / (A10 - beta);
    v2 = A20 * inv;
    e[0] = beta;
    float x0 = tau * A11;
    float x1 = tau * A21;
    float tmp2 = A21 * v2;
    x0 = x0 + tau * tmp2;
    x1 = x1 + (tau * v2) * A22;
    float dotv = x0 + x1 * v2;
    float aw = (-0.5f * tau) * dotv;
    float w0 = x0 + aw;
    float w1 = x1 + aw * v2;
    d[1] = (A11 - w0) - w0;
    float pq = v2 * w0;
    e[1] = (A21 - pq) - w1;
    float pr = v2 * w1;
    d[2] = (A22 - pr) - pr;
  }
  Z[0][0] = 1.0f; Z[0][1] = 0.0f; Z[0][2] = 0.0f;
  Z[1][0] = 0.0f; Z[1][1] = 1.0f; Z[1][2] = 0.0f;
  Z[2][0] = 0.0f; Z[2][1] = 0.0f; Z[2][2] = 1.0f;
  steqr3_f(d, e, Z);
  if (tau != 0.0f) {
    for (int j = 0; j < 3; ++j) {
      float sum = Z[1][j] + v2 * Z[2][j];
      float tw = tau * sum;
      Z[1][j] = Z[1][j] - tw;
      Z[2][j] = Z[2][j] - v2 * tw;
    }
  }
}

// ---------------- Fused kernel ----------------
__global__ __launch_bounds__(256) void fused_kernel(
    const float* __restrict__ xyz, const float* __restrict__ feats,
    const float* __restrict__ geo_w1, const float* __restrict__ geo_b1,
    const float* __restrict__ geo_g1, const float* __restrict__ geo_be1,
    const float* __restrict__ geo_w2, const float* __restrict__ geo_b2,
    const float* __restrict__ diff_w1, const float* __restrict__ diff_b1,
    const float* __restrict__ diff_g1, const float* __restrict__ diff_be1,
    const float* __restrict__ diff_w2, const float* __restrict__ diff_b2,
    const float* __restrict__ ep_w1, const float* __restrict__ ep_b1,
    const float* __restrict__ ep_w2, const float* __restrict__ ep_b2,
    const float* __restrict__ ref_w1, const float* __restrict__ ref_b1,
    const float* __restrict__ ref_g1, const float* __restrict__ ref_be1,
    float* __restrict__ out, float* __restrict__ out_prob) {

  __shared__ float tile[N_ * 3];   // 48 KB: the whole batch's xyz

  const int wave = threadIdx.x >> 6;
  const int lane = threadIdx.x & 63;
  const int p = blockIdx.x * 4 + wave;   // 4 points/block, same batch b
  const int b = p >> 12;
  const int i = p & 4095;
  const float* xb = xyz + (size_t)b * (N_ * 3);

  // Stage whole batch xyz: 3072 float4, 12 per thread, coalesced.
  {
    const float4* gsrc = (const float4*)xb;
    float4* ldst = (float4*)tile;
#pragma unroll
    for (int m = 0; m < 12; ++m)
      ldst[m * 256 + threadIdx.x] = gsrc[m * 256 + threadIdx.x];
  }

  const float qx = xb[3 * i];
  const float qy = xb[3 * i + 1];
  const float qz = xb[3 * i + 2];
  const float qxx =
      __fadd_rn(__fadd_rn(__fmul_rn(qx, qx), __fmul_rn(qy, qy)), __fmul_rn(qz, qz));
  const float nqxx = -qxx;

  __syncthreads();   // the only barrier in the kernel

  // ---- Phase 1: per-lane top-4 packed u64 keys ----
  // key = ordv(pval)<<32 | (4095-j): u64 '>' == (pval desc, j asc) exactly.
  unsigned long long pk[4] = {0ull, 0ull, 0ull, 0ull};

#pragma unroll 4
  for (int t = 0; t < 64; ++t) {
    const int j = t * 64 + lane;
    const float x = tile[j * 3];
    const float y = tile[j * 3 + 1];
    const float z = tile[j * 3 + 2];
    const float dot = __fmaf_rn(qz, z, __fmaf_rn(qy, y, __fmul_rn(qx, x)));
    const float xxj =
        __fadd_rn(__fadd_rn(__fmul_rn(x, x), __fmul_rn(y, y)), __fmul_rn(z, z));
    const float inner = __fmul_rn(-2.0f, dot);
    const float pval = __fsub_rn(__fsub_rn(nqxx, inner), xxj);
    const unsigned bits = __float_as_uint(pval);
    const unsigned ordv = bits ^ (unsigned)(((int)bits >> 31) | 0x80000000);
    const unsigned long long key =
        ((unsigned long long)ordv << 32) | (unsigned)(4095 - j);
    const bool c0 = key > pk[0], c1 = key > pk[1], c2 = key > pk[2], c3 = key > pk[3];
    pk[3] = c3 ? (c2 ? pk[2] : key) : pk[3];
    pk[2] = c2 ? (c1 ? pk[1] : key) : pk[2];
    pk[1] = c1 ? (c0 ? pk[0] : key) : pk[1];
    pk[0] = c0 ? key : pk[0];
  }

  // ---- Phase 2: 16-pop tournament merge over per-lane top-4 lists ----
  int nidx[K_];
  int h = 0;
#pragma unroll
  for (int k = 0; k < K_; ++k) {
    unsigned long long v = pk[0];
    int ln = lane;
#pragma unroll
    for (int off = 32; off >= 1; off >>= 1) {
      unsigned long long ov = __shfl_xor(v, off, 64);
      int ol = __shfl_xor(ln, off, 64);
      if (ov > v) { v = ov; ln = ol; }   // keys distinct => no ties
    }
    nidx[k] = (4095 - (int)(unsigned)(v & 0xFFFFFFFFull)) & (N_ - 1);
    if (lane == ln) {
      pk[0] = pk[1]; pk[1] = pk[2]; pk[2] = pk[3]; pk[3] = 0ull;
      ++h;
    }
  }
  // Safety: if any lane had all 4 entries popped, its 5th-best might belong in
  // the top-16 -> exact fallback with 16-deep lists (rare, wave-uniform).
  if (__ballot(h >= 4) != 0ull) {
    unsigned long long q[K_];
#pragma unroll
    for (int k = 0; k < K_; ++k) q[k] = 0ull;
    for (int t = 0; t < 64; ++t) {
      const int j = t * 64 + lane;
      const float x = tile[j * 3];
      const float y = tile[j * 3 + 1];
      const float z = tile[j * 3 + 2];
      const float dot = __fmaf_rn(qz, z, __fmaf_rn(qy, y, __fmul_rn(qx, x)));
      const float xxj =
          __fadd_rn(__fadd_rn(__fmul_rn(x, x), __fmul_rn(y, y)), __fmul_rn(z, z));
      const float inner = __fmul_rn(-2.0f, dot);
      const float pval = __fsub_rn(__fsub_rn(nqxx, inner), xxj);
      const unsigned bits = __float_as_uint(pval);
      const unsigned ordv = bits ^ (unsigned)(((int)bits >> 31) | 0x80000000);
      const unsigned long long key =
          ((unsigned long long)ordv << 32) | (unsigned)(4095 - j);
      bool c[K_];
#pragma unroll
      for (int s = 0; s < K_; ++s) c[s] = key > q[s];
#pragma unroll
      for (int s = K_ - 1; s >= 1; --s)
        q[s] = c[s] ? (c[s - 1] ? q[s - 1] : key) : q[s];
      q[0] = c[0] ? key : q[0];
    }
#pragma unroll
    for (int k = 0; k < K_; ++k) {
      unsigned long long v = q[0];
      int ln = lane;
#pragma unroll
      for (int off = 32; off >= 1; off >>= 1) {
        unsigned long long ov = __shfl_xor(v, off, 64);
        int ol = __shfl_xor(ln, off, 64);
        if (ov > v) { v = ov; ln = ol; }
      }
      nidx[k] = (4095 - (int)(unsigned)(v & 0xFFFFFFFFull)) & (N_ - 1);
      if (lane == ln) {
#pragma unroll
        for (int s = 0; s < K_ - 1; ++s) q[s] = q[s + 1];
        q[K_ - 1] = 0ull;
      }
    }
  }

  // ---- Phase 3: rel_pos/cov/eig/gfeat (byte-identical math to R6) ----
  float c00 = 0, c01 = 0, c02 = 0, c11 = 0, c12 = 0, c22 = 0;
  float mrx = 0, mry = 0, mrz = 0, md = 0;
#pragma unroll
  for (int k = 0; k < K_; ++k) {
    const int j = nidx[k];
    const float rx = __fsub_rn(tile[j * 3], qx);
    const float ry = __fsub_rn(tile[j * 3 + 1], qy);
    const float rz = __fsub_rn(tile[j * 3 + 2], qz);
    c00 = __fadd_rn(c00, __fmul_rn(rx, rx));
    c01 = __fadd_rn(c01, __fmul_rn(rx, ry));
    c02 = __fadd_rn(c02, __fmul_rn(rx, rz));
    c11 = __fadd_rn(c11, __fmul_rn(ry, ry));
    c12 = __fadd_rn(c12, __fmul_rn(ry, rz));
    c22 = __fadd_rn(c22, __fmul_rn(rz, rz));
    mrx = __fadd_rn(mrx, rx);
    mry = __fadd_rn(mry, ry);
    mrz = __fadd_rn(mrz, rz);
    const float nn = __fadd_rn(__fadd_rn(__fmul_rn(rx, rx), __fmul_rn(ry, ry)),
                               __fmul_rn(rz, rz));
    md = __fadd_rn(md, sqrtf(nn));
  }
  const float s16 = 0.0625f;
  float Z[3][3];
  eig3_f(__fmul_rn(c00, s16), __fmul_rn(c01, s16), __fmul_rn(c02, s16),
         __fmul_rn(c11, s16), __fmul_rn(c12, s16), __fmul_rn(c22, s16), Z);
  float gf[10];
  gf[0] = Z[0][0]; gf[1] = Z[1][0]; gf[2] = Z[2][0];
  gf[3] = Z[0][2]; gf[4] = Z[1][2]; gf[5] = Z[2][2];
  gf[6] = __fmul_rn(mrx, s16); gf[7] = __fmul_rn(mry, s16);
  gf[8] = __fmul_rn(mrz, s16);
  gf[9] = __fmul_rn(md, s16);

  // ---- Phase 4: geo MLP (no LDS: shuffle broadcast, same sum order) ----
  float acc = 0.0f;
#pragma unroll
  for (int ii = 0; ii < 10; ++ii) acc += gf[ii] * geo_w1[ii * 64 + lane];
  acc += geo_b1[lane];
  float yr;
  {
    float m = wave_sum64(acc) * (1.0f / 64.0f);
    float xm = acc - m;
    float var = wave_sum64(xm * xm) * (1.0f / 64.0f);
    float yv = xm * (1.0f / sqrtf(var + 1e-5f)) * geo_g1[lane] + geo_be1[lane];
    yr = fmaxf(yv, 0.0f);
  }
  float ge = 0.0f;
#pragma unroll 8
  for (int jj = 0; jj < 64; ++jj) ge += __shfl(yr, jj, 64) * geo_w2[jj * 64 + lane];
  ge += geo_b2[lane];

  // ---- Phase 5: feat_diff + diff MLP ----
  const float* fb = feats + (size_t)b * N_ * C_;
  const float* fi = fb + (size_t)i * C_;
  const float f0 = fi[lane];
  const float f1 = fi[64 + lane];
  float s0 = 0.0f, s1 = 0.0f;
#pragma unroll
  for (int k = 0; k < K_; ++k) {
    const float* fj = fb + (size_t)nidx[k] * C_;
    s0 += fabsf(f0 - fj[lane]);
    s1 += fabsf(f1 - fj[64 + lane]);
  }
  s0 *= (1.0f / 16.0f);
  s1 *= (1.0f / 16.0f);
  float acc2 = 0.0f;
#pragma unroll 8
  for (int c = 0; c < 64; ++c) acc2 += __shfl(s0, c, 64) * diff_w1[c * 64 + lane];
#pragma unroll 8
  for (int c = 64; c < 128; ++c) acc2 += __shfl(s1, c - 64, 64) * diff_w1[c * 64 + lane];
  acc2 += diff_b1[lane];
  float yr2;
  {
    float m = wave_sum64(acc2) * (1.0f / 64.0f);
    float xm = acc2 - m;
    float var = wave_sum64(xm * xm) * (1.0f / 64.0f);
    float yv = xm * (1.0f / sqrtf(var + 1e-5f)) * diff_g1[lane] + diff_be1[lane];
    yr2 = fmaxf(yv, 0.0f);
  }
  float de = 0.0f;
#pragma unroll 8
  for (int jj = 0; jj < 64; ++jj) de += __shfl(yr2, jj, 64) * diff_w2[jj * 64 + lane];
  de += diff_b2[lane];

  // ---- Phase 6: edge prob + enhanced + refine ----
  // ep matvec: all lanes compute unit (lane&31) uniformly (convergent shuffles);
  // lanes >=32 duplicate and are masked out of the reduction.
  {
    const int u = lane & 31;
    float a = 0.0f;
#pragma unroll 8
    for (int c = 0; c < 64; ++c) a += __shfl(ge, c, 64) * ep_w1[c * 32 + u];
#pragma unroll 8
    for (int c = 64; c < 128; ++c) a += __shfl(de, c - 64, 64) * ep_w1[c * 32 + u];
    a += ep_b1[u];
    float hh = (lane < 32) ? fmaxf(a, 0.0f) * ep_w2[u] : 0.0f;
    float tsum = wave_sum64(hh) + ep_b2[0];
    float prob = 1.0f / (1.0f + expf(-tsum));

    const float gep = ge * prob;
    const float dep = de * prob;
    float a0 = 0.0f, a1 = 0.0f;
#pragma unroll 4
    for (int c = 0; c < 64; ++c) {
      float ec = __shfl(f0, c, 64);
      a0 += ec * ref_w1[c * 128 + lane];
      a1 += ec * ref_w1[c * 128 + 64 + lane];
    }
#pragma unroll 4
    for (int c = 64; c < 128; ++c) {
      float ec = __shfl(f1, c - 64, 64);
      a0 += ec * ref_w1[c * 128 + lane];
      a1 += ec * ref_w1[c * 128 + 64 + lane];
    }
#pragma unroll 4
    for (int c = 128; c < 192; ++c) {
      float ec = __shfl(gep, c - 128, 64);
      a0 += ec * ref_w1[c * 128 + lane];
      a1 += ec * ref_w1[c * 128 + 64 + lane];
    }
#pragma unroll 4
    for (int c = 192; c < 256; ++c) {
      float ec = __shfl(dep, c - 192, 64);
      a0 += ec * ref_w1[c * 128 + lane];
      a1 += ec * ref_w1[c * 128 + 64 + lane];
    }
    a0 += ref_b1[lane];
    a1 += ref_b1[64 + lane];
    float mm2 = wave_sum64(a0 + a1) * (1.0f / 128.0f);
    float d0 = a0 - mm2, d1 = a1 - mm2;
    float var2 = wave_sum64(d0 * d0 + d1 * d1) * (1.0f / 128.0f);
    float rs = 1.0f / sqrtf(var2 + 1e-5f);
    float y0 = d0 * rs * ref_g1[lane] + ref_be1[lane];
    float y1 = d1 * rs * ref_g1[64 + lane] + ref_be1[64 + lane];
    y0 = fmaxf(y0, 0.0f) + f0;
    y1 = fmaxf(y1, 0.0f) + f1;
    out[(size_t)p * 128 + lane] = y0;
    out[(size_t)p * 128 + 64 + lane] = y1;
    if (lane == 0) out_prob[p] = prob;
  }
}

extern "C" void kernel_launch(void* const* d_in, const int* in_sizes, int n_in,
                              void* d_out, int out_size, void* d_ws, size_t ws_size,
                              hipStream_t stream) {
  const float* xyz = (const float*)d_in[0];
  const float* features = (const float*)d_in[1];
  const float* geo_w1 = (const float*)d_in[2];
  const float* geo_b1 = (const float*)d_in[3];
  const float* geo_g1 = (const float*)d_in[4];
  const float* geo_be1 = (const float*)d_in[5];
  const float* geo_w2 = (const float*)d_in[6];
  const float* geo_b2 = (const float*)d_in[7];
  const float* diff_w1 = (const float*)d_in[8];
  const float* diff_b1 = (const float*)d_in[9];
  const float* diff_g1 = (const float*)d_in[10];
  const float* diff_be1 = (const float*)d_in[11];
  const float* diff_w2 = (const float*)d_in[12];
  const float* diff_b2 = (const float*)d_in[13];
  const float* ep_w1 = (const float*)d_in[14];
  const float* ep_b1 = (const float*)d_in[15];
  const float* ep_w2 = (const float*)d_in[16];
  const float* ep_b2 = (const float*)d_in[17];
  const float* ref_w1 = (const float*)d_in[18];
  const float* ref_b1 = (const float*)d_in[19];
  const float* ref_g1 = (const float*)d_in[20];
  const float* ref_be1 = (const float*)d_in[21];

  float* out = (float*)d_out;
  float* out_prob = out + (size_t)NPT * C_;

  fused_kernel<<<dim3(NPT / 4), dim3(256), 0, stream>>>(
      xyz, features, geo_w1, geo_b1, geo_g1, geo_be1, geo_w2, geo_b2, diff_w1,
      diff_b1, diff_g1, diff_be1, diff_w2, diff_b2, ep_w1, ep_b1, ep_w2, ep_b2,
      ref_w1, ref_b1, ref_g1, ref_be1, out, out_prob);
}